// Round 6
// baseline (457.165 us; speedup 1.0000x reference)
//
#include <hip/hip_runtime.h>
#include <hip/hip_bf16.h>
#include <stdint.h>

#define T_TOK 1024
#define HID   1024
#define INT_  4096
#define NE    8

typedef __attribute__((ext_vector_type(4))) float f32x4;
typedef __attribute__((ext_vector_type(8))) short short8;

__device__ int g_tok[NE][T_TOK];   // compacted token list per expert
__device__ int g_cnt[NE];

__device__ __forceinline__ uint32_t pack2bf(float a, float b) {
  unsigned short ua = __builtin_bit_cast(unsigned short, (__bf16)a);
  unsigned short ub = __builtin_bit_cast(unsigned short, (__bf16)b);
  return (uint32_t)ua | ((uint32_t)ub << 16);
}

// ---------------- Kernel 0: per-expert token compaction ---------------------
__global__ void k0_compact(const int* __restrict__ mask)  // [T_TOK][NE]
{
  const int w    = threadIdx.x >> 6;
  const int lane = threadIdx.x & 63;
  if (w >= NE) return;
  const unsigned long long ltmask = (1ull << lane) - 1ull;
  int base = 0;
  #pragma unroll
  for (int c = 0; c < T_TOK / 64; ++c) {
    const int t = c * 64 + lane;
    const bool pred = mask[t * NE + w] != 0;
    const unsigned long long bal = __ballot(pred);
    if (pred) g_tok[w][base + __popcll(bal & ltmask)] = t;
    base += __popcll(bal);
  }
  if (lane == 0) g_cnt[w] = base;
}

// ---------------- Kernel 1: act[e,slot,i] = up * silu(gate) -----------------
// grid (INT_/64, T_TOK/128, NE), 256 threads, LB(256,2) — VGPR cap 256, no spill.
// Single 32 KB LDS buffer -> up to 5 blocks/CU co-resident (TLP latency hiding).
// Block tile M=128 x N=64 (gate AND up); wave 64m x 32n.
__global__ __launch_bounds__(256, 2)
void k1_gateup(const float* __restrict__ x,        // [T_TOK][HID]
               const float* __restrict__ wgu,      // [NE][HID][2*INT_]
               unsigned short* __restrict__ act)   // [NE][T_TOK][INT_] bf16 bits
{
  const int e   = blockIdx.z;
  const int cnt = g_cnt[e];
  const int mt  = blockIdx.y;
  const int t0  = mt * 128;
  if (t0 >= cnt) return;

  __shared__ char sA [128 * 64 * 2];   // [m][k] bf16, swizzled  (16 KB)
  __shared__ char sBg[64 * 64 * 2];    // [n][k] bf16, swizzled  (8 KB)
  __shared__ char sBu[64 * 64 * 2];    // (8 KB)

  const int nt   = blockIdx.x;
  const int tid  = threadIdx.x;
  const int lane = tid & 63;
  const int wv   = tid >> 6;
  const int wr   = (wv >> 1) * 64;     // wave row offset (m)
  const int wc   = (wv & 1)  * 32;     // wave col offset (n)

  const float* wb = wgu + (size_t)e * HID * (2 * INT_);
  const int n0 = nt * 64;

  f32x4 accg[4][2], accu[4][2];
  #pragma unroll
  for (int i = 0; i < 4; ++i)
    #pragma unroll
    for (int j = 0; j < 2; ++j) {
      accg[i][j] = (f32x4){0.f, 0.f, 0.f, 0.f};
      accu[i][j] = (f32x4){0.f, 0.f, 0.f, 0.f};
    }

  const int a_m = tid >> 4;            // 0..15
  const int a_k = (tid & 15) * 4;      // f32 elems 0..60
  const int b_n = (tid >> 4) * 4;      // 0..60
  const int b_k = (tid & 15) * 4;      // 0..60

  int tokr[8];
  #pragma unroll
  for (int p = 0; p < 8; ++p) tokr[p] = g_tok[e][t0 + p * 16 + a_m];

  for (int kt = 0; kt < HID; kt += 64) {
    // ---- stage A: gathered x rows [128][64] f32 -> bf16 LDS [m][k]
    #pragma unroll
    for (int p = 0; p < 8; ++p) {
      const int m = p * 16 + a_m;
      f32x4 v = *(const f32x4*)(x + (size_t)tokr[p] * HID + kt + a_k);
      uint2 w; w.x = pack2bf(v[0], v[1]); w.y = pack2bf(v[2], v[3]);
      *(uint2*)(sA + m * 128 + ((a_k * 2) ^ ((m & 7) << 4))) = w;
    }
    // ---- stage Bg/Bu: 4 k-rows each of gate & up -> transposed LDS [n][k]
    {
      const float* s_ = wb + (size_t)(kt + b_k) * (2 * INT_) + n0 + b_n;
      f32x4 g0 = *(const f32x4*)(s_);
      f32x4 g1 = *(const f32x4*)(s_ + (2 * INT_));
      f32x4 g2 = *(const f32x4*)(s_ + 2 * (2 * INT_));
      f32x4 g3 = *(const f32x4*)(s_ + 3 * (2 * INT_));
      f32x4 u0 = *(const f32x4*)(s_ + INT_);
      f32x4 u1 = *(const f32x4*)(s_ + INT_ + (2 * INT_));
      f32x4 u2 = *(const f32x4*)(s_ + INT_ + 2 * (2 * INT_));
      f32x4 u3 = *(const f32x4*)(s_ + INT_ + 3 * (2 * INT_));
      #pragma unroll
      for (int n = 0; n < 4; ++n) {
        const int row = b_n + n;
        const int off = row * 128 + ((b_k * 2) ^ ((row & 7) << 4));
        uint2 wg; wg.x = pack2bf(g0[n], g1[n]); wg.y = pack2bf(g2[n], g3[n]);
        *(uint2*)(sBg + off) = wg;
        uint2 wu; wu.x = pack2bf(u0[n], u1[n]); wu.y = pack2bf(u2[n], u3[n]);
        *(uint2*)(sBu + off) = wu;
      }
    }
    __syncthreads();
    // ---- compute tile kt from LDS
    #pragma unroll
    for (int ks = 0; ks < 2; ++ks) {
      const int kfb = ks * 64 + ((lane >> 4) << 4);
      short8 af[4], bg[2], bu[2];
      #pragma unroll
      for (int i = 0; i < 4; ++i) {
        const int r = wr + i * 16 + (lane & 15);
        af[i] = *(const short8*)(sA + r * 128 + (kfb ^ ((r & 7) << 4)));
      }
      #pragma unroll
      for (int j = 0; j < 2; ++j) {
        const int r = wc + j * 16 + (lane & 15);
        const int off = r * 128 + (kfb ^ ((r & 7) << 4));
        bg[j] = *(const short8*)(sBg + off);
        bu[j] = *(const short8*)(sBu + off);
      }
      #pragma unroll
      for (int i = 0; i < 4; ++i)
        #pragma unroll
        for (int j = 0; j < 2; ++j) {
          accg[i][j] = __builtin_amdgcn_mfma_f32_16x16x32_bf16(af[i], bg[j], accg[i][j], 0, 0, 0);
          accu[i][j] = __builtin_amdgcn_mfma_f32_16x16x32_bf16(af[i], bu[j], accu[i][j], 0, 0, 0);
        }
    }
    __syncthreads();
  }

  // ---- epilogue: act = up * silu(gate)
  unsigned short* ab = act + (size_t)e * T_TOK * INT_;
  #pragma unroll
  for (int i = 0; i < 4; ++i) {
    #pragma unroll
    for (int r = 0; r < 4; ++r) {
      const int slot = t0 + wr + i * 16 + ((lane >> 4) << 2) + r;
      if (slot < cnt) {
        #pragma unroll
        for (int j = 0; j < 2; ++j) {
          const int col = n0 + wc + j * 16 + (lane & 15);
          const float g = accg[i][j][r];
          const float u = accu[i][j][r];
          const float s = u * g / (1.f + __expf(-g));
          ab[(size_t)slot * INT_ + col] = __builtin_bit_cast(unsigned short, (__bf16)s);
        }
      }
    }
  }
}

// ---------------- Kernel 2: out[tok[slot],h] += act[e,slot] @ w_down[e] -----
// grid (HID/128, (T_TOK/128)*4, NE), 256 threads. K split 4-way (1024 each),
// direct staging, atomicAdd merge. UNCHANGED from R4 (~120us confirmed).
__global__ __launch_bounds__(256, 2)
void k2_down(const unsigned short* __restrict__ act,  // [NE][T_TOK][INT_] bf16
             const float* __restrict__ wd,            // [NE][INT_][HID]
             float* __restrict__ out)                 // [T_TOK][HID]
{
  const int e   = blockIdx.z;
  const int cnt = g_cnt[e];
  const int mt  = blockIdx.y >> 2;
  const int ks4 = blockIdx.y & 3;      // K-slice 0..3
  const int t0  = mt * 128;
  if (t0 >= cnt) return;

  __shared__ char sA[128 * 64 * 2];    // [m][k] bf16
  __shared__ char sB[128 * 64 * 2];    // [n][k] bf16

  const int nt   = blockIdx.x;
  const int tid  = threadIdx.x;
  const int lane = tid & 63;
  const int wv   = tid >> 6;
  const int wr   = (wv >> 1) * 64;
  const int wc   = (wv & 1)  * 64;

  const unsigned short* ab = act + (size_t)e * T_TOK * INT_;
  const float* wb = wd + (size_t)e * INT_ * HID;
  const int n0 = nt * 128;

  f32x4 acc[4][4];
  #pragma unroll
  for (int i = 0; i < 4; ++i)
    #pragma unroll
    for (int j = 0; j < 4; ++j) acc[i][j] = (f32x4){0.f, 0.f, 0.f, 0.f};

  const int a_m = tid >> 3;            // 0..31
  const int a_k = (tid & 7) * 8;       // bf16 elems 0..56
  const int b_n = (tid >> 3) * 4;      // 0..124
  const int b_k = (tid & 7) * 4;       // 0..28

  const int kbeg = ks4 * (INT_ / 4);
  const int kend = kbeg + (INT_ / 4);

  for (int kt = kbeg; kt < kend; kt += 64) {
    // ---- stage A: act tile (already bf16), direct 16B copies
    #pragma unroll
    for (int p = 0; p < 4; ++p) {
      const int m = p * 32 + a_m;
      uint4 v = *(const uint4*)(ab + (size_t)(t0 + m) * INT_ + kt + a_k);
      *(uint4*)(sA + m * 128 + ((a_k * 2) ^ ((m & 7) << 4))) = v;
    }
    // ---- stage B: w_down rows -> transposed bf16 LDS [n][k]
    #pragma unroll
    for (int p = 0; p < 2; ++p) {
      const int kk = p * 32 + b_k;
      const float* src = wb + (size_t)(kt + kk) * HID + n0 + b_n;
      f32x4 r0 = *(const f32x4*)(src);
      f32x4 r1 = *(const f32x4*)(src + HID);
      f32x4 r2 = *(const f32x4*)(src + 2 * HID);
      f32x4 r3 = *(const f32x4*)(src + 3 * HID);
      #pragma unroll
      for (int n = 0; n < 4; ++n) {
        const int row = b_n + n;
        uint2 w; w.x = pack2bf(r0[n], r1[n]); w.y = pack2bf(r2[n], r3[n]);
        *(uint2*)(sB + row * 128 + ((kk * 2) ^ ((row & 7) << 4))) = w;
      }
    }
    __syncthreads();
    #pragma unroll
    for (int ks = 0; ks < 2; ++ks) {
      const int kfb = ks * 64 + ((lane >> 4) << 4);
      short8 af[4], bf[4];
      #pragma unroll
      for (int i = 0; i < 4; ++i) {
        const int r = wr + i * 16 + (lane & 15);
        af[i] = *(const short8*)(sA + r * 128 + (kfb ^ ((r & 7) << 4)));
      }
      #pragma unroll
      for (int i = 0; i < 4; ++i) {
        const int r = wc + i * 16 + (lane & 15);
        bf[i] = *(const short8*)(sB + r * 128 + (kfb ^ ((r & 7) << 4)));
      }
      #pragma unroll
      for (int i = 0; i < 4; ++i)
        #pragma unroll
        for (int j = 0; j < 4; ++j)
          acc[i][j] = __builtin_amdgcn_mfma_f32_16x16x32_bf16(af[i], bf[j], acc[i][j], 0, 0, 0);
    }
    __syncthreads();
  }

  // ---- epilogue: scatter-accumulate valid rows into out
  #pragma unroll
  for (int i = 0; i < 4; ++i) {
    #pragma unroll
    for (int r = 0; r < 4; ++r) {
      const int slot = t0 + wr + i * 16 + ((lane >> 4) << 2) + r;
      if (slot < cnt) {
        const int token = g_tok[e][slot];
        #pragma unroll
        for (int j = 0; j < 4; ++j) {
          const int col = n0 + wc + j * 16 + (lane & 15);
          atomicAdd(out + (size_t)token * HID + col, acc[i][j][r]);
        }
      }
    }
  }
}

extern "C" void kernel_launch(void* const* d_in, const int* in_sizes, int n_in,
                              void* d_out, int out_size, void* d_ws, size_t ws_size,
                              hipStream_t stream) {
  const float* x   = (const float*)d_in[0];
  const int*   idx = (const int*)d_in[1];
  const float* wgu = (const float*)d_in[2];
  const float* wd  = (const float*)d_in[3];
  float* out = (float*)d_out;
  unsigned short* act = (unsigned short*)d_ws;   // 64 MB

  hipMemsetAsync(d_out, 0, (size_t)out_size * sizeof(float), stream);

  k0_compact<<<1, 512, 0, stream>>>(idx);

  dim3 g1(INT_ / 64, T_TOK / 128, NE);        // (64, 8, 8)
  k1_gateup<<<g1, dim3(256), 0, stream>>>(x, wgu, act);

  dim3 g2(HID / 128, (T_TOK / 128) * 4, NE);  // (8, 32, 8) — y = mt*4|ks
  k2_down<<<g2, dim3(256), 0, stream>>>(act, wd, out);
}

// Round 7
// 373.751 us; speedup vs baseline: 1.2232x; 1.2232x over previous
//
#include <hip/hip_runtime.h>
#include <hip/hip_bf16.h>
#include <stdint.h>

#define T_TOK 1024
#define HID   1024
#define INT_  4096
#define NE    8

typedef __attribute__((ext_vector_type(4))) float f32x4;
typedef __attribute__((ext_vector_type(8))) short short8;

__device__ int g_tok[NE][T_TOK];   // compacted token list per expert
__device__ int g_cnt[NE];

__device__ __forceinline__ uint32_t pack2bf(float a, float b) {
  unsigned short ua = __builtin_bit_cast(unsigned short, (__bf16)a);
  unsigned short ub = __builtin_bit_cast(unsigned short, (__bf16)b);
  return (uint32_t)ua | ((uint32_t)ub << 16);
}

// ---------------- Kernel 0: per-expert token compaction ---------------------
__global__ void k0_compact(const int* __restrict__ mask)  // [T_TOK][NE]
{
  const int w    = threadIdx.x >> 6;
  const int lane = threadIdx.x & 63;
  if (w >= NE) return;
  const unsigned long long ltmask = (1ull << lane) - 1ull;
  int base = 0;
  #pragma unroll
  for (int c = 0; c < T_TOK / 64; ++c) {
    const int t = c * 64 + lane;
    const bool pred = mask[t * NE + w] != 0;
    const unsigned long long bal = __ballot(pred);
    if (pred) g_tok[w][base + __popcll(bal & ltmask)] = t;
    base += __popcll(bal);
  }
  if (lane == 0) g_cnt[w] = base;
}

// ---------------- Kernel 1: act[e,slot,i] = up * silu(gate) -----------------
// grid (INT_/128, T_TOK/256, NE), 512 threads (8 waves, 2m x 4n).
// Block tile M=256 x 128 act-cols (gate+up => 256 B-cols). LDS 64 KB.
// Staged bytes per MFMA = 0.67x of the R2 128x256 tile.
__global__ __launch_bounds__(512, 1)
void k1_gateup(const float* __restrict__ x,        // [T_TOK][HID]
               const float* __restrict__ wgu,      // [NE][HID][2*INT_]
               unsigned short* __restrict__ act)   // [NE][T_TOK][INT_] bf16 bits
{
  const int e   = blockIdx.z;
  const int cnt = g_cnt[e];
  const int mt  = blockIdx.y;
  const int t0  = mt * 256;
  if (t0 >= cnt) return;

  __shared__ char sA [256 * 64 * 2];   // [m][k] bf16, swizzled (32 KB)
  __shared__ char sBg[128 * 64 * 2];   // [n][k] bf16, swizzled (16 KB)
  __shared__ char sBu[128 * 64 * 2];   // (16 KB)

  const int nt   = blockIdx.x;         // 0..31
  const int tid  = threadIdx.x;
  const int lane = tid & 63;
  const int wv   = tid >> 6;           // 0..7
  const int wm   = (wv >> 2) * 128;    // wave m offset: 0 / 128
  const int wn   = (wv & 3) * 32;      // wave n offset: 0/32/64/96

  const float* wb = wgu + (size_t)e * HID * (2 * INT_);
  const int n0 = nt * 128;

  f32x4 accg[8][2], accu[8][2];
  #pragma unroll
  for (int i = 0; i < 8; ++i)
    #pragma unroll
    for (int j = 0; j < 2; ++j) {
      accg[i][j] = (f32x4){0.f, 0.f, 0.f, 0.f};
      accu[i][j] = (f32x4){0.f, 0.f, 0.f, 0.f};
    }

  const int a_m = tid >> 4;            // 0..31
  const int a_k = (tid & 15) * 4;      // f32 elems 0..60
  const int b_n = (tid >> 4) * 4;      // 0..124
  const int b_k = (tid & 15) * 4;      // 0..60

  int tokr[8];
  #pragma unroll
  for (int p = 0; p < 8; ++p) tokr[p] = g_tok[e][t0 + p * 32 + a_m];

  for (int kt = 0; kt < HID; kt += 64) {
    // ---- stage A: gathered x rows [256][64] f32 -> bf16 LDS [m][k]
    #pragma unroll
    for (int p = 0; p < 8; ++p) {
      const int m = p * 32 + a_m;
      f32x4 v = *(const f32x4*)(x + (size_t)tokr[p] * HID + kt + a_k);
      uint2 w; w.x = pack2bf(v[0], v[1]); w.y = pack2bf(v[2], v[3]);
      *(uint2*)(sA + m * 128 + ((a_k * 2) ^ ((m & 7) << 4))) = w;
    }
    // ---- stage Bg/Bu: [64k][128n] each of gate & up -> transposed LDS [n][k]
    {
      const float* s_ = wb + (size_t)(kt + b_k) * (2 * INT_) + n0 + b_n;
      f32x4 g0 = *(const f32x4*)(s_);
      f32x4 g1 = *(const f32x4*)(s_ + (2 * INT_));
      f32x4 g2 = *(const f32x4*)(s_ + 2 * (2 * INT_));
      f32x4 g3 = *(const f32x4*)(s_ + 3 * (2 * INT_));
      f32x4 u0 = *(const f32x4*)(s_ + INT_);
      f32x4 u1 = *(const f32x4*)(s_ + INT_ + (2 * INT_));
      f32x4 u2 = *(const f32x4*)(s_ + INT_ + 2 * (2 * INT_));
      f32x4 u3 = *(const f32x4*)(s_ + INT_ + 3 * (2 * INT_));
      #pragma unroll
      for (int n = 0; n < 4; ++n) {
        const int row = b_n + n;
        const int off = row * 128 + ((b_k * 2) ^ ((row & 7) << 4));
        uint2 wg; wg.x = pack2bf(g0[n], g1[n]); wg.y = pack2bf(g2[n], g3[n]);
        *(uint2*)(sBg + off) = wg;
        uint2 wu; wu.x = pack2bf(u0[n], u1[n]); wu.y = pack2bf(u2[n], u3[n]);
        *(uint2*)(sBu + off) = wu;
      }
    }
    __syncthreads();
    // ---- compute tile kt from LDS
    #pragma unroll
    for (int ks = 0; ks < 2; ++ks) {
      const int kfb = ks * 64 + ((lane >> 4) << 4);
      short8 af[8], bg[2], bu[2];
      #pragma unroll
      for (int i = 0; i < 8; ++i) {
        const int r = wm + i * 16 + (lane & 15);
        af[i] = *(const short8*)(sA + r * 128 + (kfb ^ ((r & 7) << 4)));
      }
      #pragma unroll
      for (int j = 0; j < 2; ++j) {
        const int r = wn + j * 16 + (lane & 15);
        const int off = r * 128 + (kfb ^ ((r & 7) << 4));
        bg[j] = *(const short8*)(sBg + off);
        bu[j] = *(const short8*)(sBu + off);
      }
      #pragma unroll
      for (int i = 0; i < 8; ++i)
        #pragma unroll
        for (int j = 0; j < 2; ++j) {
          accg[i][j] = __builtin_amdgcn_mfma_f32_16x16x32_bf16(af[i], bg[j], accg[i][j], 0, 0, 0);
          accu[i][j] = __builtin_amdgcn_mfma_f32_16x16x32_bf16(af[i], bu[j], accu[i][j], 0, 0, 0);
        }
    }
    __syncthreads();
  }

  // ---- epilogue: act = up * silu(gate)
  unsigned short* ab = act + (size_t)e * T_TOK * INT_;
  #pragma unroll
  for (int i = 0; i < 8; ++i) {
    #pragma unroll
    for (int r = 0; r < 4; ++r) {
      const int slot = t0 + wm + i * 16 + ((lane >> 4) << 2) + r;
      if (slot < cnt) {
        #pragma unroll
        for (int j = 0; j < 2; ++j) {
          const int col = n0 + wn + j * 16 + (lane & 15);
          const float g = accg[i][j][r];
          const float u = accu[i][j][r];
          const float s = u * g / (1.f + __expf(-g));
          ab[(size_t)slot * INT_ + col] = __builtin_bit_cast(unsigned short, (__bf16)s);
        }
      }
    }
  }
}

// ---------------- Kernel 2: out[tok[slot],h] += act[e,slot] @ w_down[e] -----
// grid (HID/128, (T_TOK/256)*4, NE), 512 threads (8 waves, 4m x 2n).
// Block tile M=256 x N=128, K split 4-way (1024 each). LDS 48 KB.
__global__ __launch_bounds__(512, 1)
void k2_down(const unsigned short* __restrict__ act,  // [NE][T_TOK][INT_] bf16
             const float* __restrict__ wd,            // [NE][INT_][HID]
             float* __restrict__ out)                 // [T_TOK][HID]
{
  const int e   = blockIdx.z;
  const int cnt = g_cnt[e];
  const int mt  = blockIdx.y >> 2;     // 0..3
  const int ks4 = blockIdx.y & 3;      // K-slice 0..3
  const int t0  = mt * 256;
  if (t0 >= cnt) return;

  __shared__ char sA[256 * 64 * 2];    // [m][k] bf16 (32 KB)
  __shared__ char sB[128 * 64 * 2];    // [n][k] bf16 (16 KB)

  const int nt   = blockIdx.x;         // 0..7
  const int tid  = threadIdx.x;
  const int lane = tid & 63;
  const int wv   = tid >> 6;           // 0..7
  const int wm   = (wv >> 1) * 64;     // 0/64/128/192
  const int wn2  = (wv & 1) * 64;      // 0/64

  const unsigned short* ab = act + (size_t)e * T_TOK * INT_;
  const float* wb = wd + (size_t)e * INT_ * HID;
  const int n0 = nt * 128;

  f32x4 acc[4][4];
  #pragma unroll
  for (int i = 0; i < 4; ++i)
    #pragma unroll
    for (int j = 0; j < 4; ++j) acc[i][j] = (f32x4){0.f, 0.f, 0.f, 0.f};

  const int a_m = tid >> 3;            // 0..63
  const int a_k = (tid & 7) * 8;       // bf16 elems 0..56
  const int b_n = (tid >> 4) * 4;      // 0..124
  const int b_k = (tid & 15) * 4;      // 0..60

  const int kbeg = ks4 * (INT_ / 4);
  const int kend = kbeg + (INT_ / 4);

  for (int kt = kbeg; kt < kend; kt += 64) {
    // ---- stage A: act tile [256][64] (already bf16), direct 16B copies
    #pragma unroll
    for (int p = 0; p < 4; ++p) {
      const int m = p * 64 + a_m;
      uint4 v = *(const uint4*)(ab + (size_t)(t0 + m) * INT_ + kt + a_k);
      *(uint4*)(sA + m * 128 + ((a_k * 2) ^ ((m & 7) << 4))) = v;
    }
    // ---- stage B: w_down [64k][128n] rows -> transposed bf16 LDS [n][k]
    {
      const float* src = wb + (size_t)(kt + b_k) * HID + n0 + b_n;
      f32x4 r0 = *(const f32x4*)(src);
      f32x4 r1 = *(const f32x4*)(src + HID);
      f32x4 r2 = *(const f32x4*)(src + 2 * HID);
      f32x4 r3 = *(const f32x4*)(src + 3 * HID);
      #pragma unroll
      for (int n = 0; n < 4; ++n) {
        const int row = b_n + n;
        uint2 w; w.x = pack2bf(r0[n], r1[n]); w.y = pack2bf(r2[n], r3[n]);
        *(uint2*)(sB + row * 128 + ((b_k * 2) ^ ((row & 7) << 4))) = w;
      }
    }
    __syncthreads();
    #pragma unroll
    for (int ks = 0; ks < 2; ++ks) {
      const int kfb = ks * 64 + ((lane >> 4) << 4);
      short8 af[4], bf[4];
      #pragma unroll
      for (int i = 0; i < 4; ++i) {
        const int r = wm + i * 16 + (lane & 15);
        af[i] = *(const short8*)(sA + r * 128 + (kfb ^ ((r & 7) << 4)));
      }
      #pragma unroll
      for (int j = 0; j < 4; ++j) {
        const int r = wn2 + j * 16 + (lane & 15);
        bf[j] = *(const short8*)(sB + r * 128 + (kfb ^ ((r & 7) << 4)));
      }
      #pragma unroll
      for (int i = 0; i < 4; ++i)
        #pragma unroll
        for (int j = 0; j < 4; ++j)
          acc[i][j] = __builtin_amdgcn_mfma_f32_16x16x32_bf16(af[i], bf[j], acc[i][j], 0, 0, 0);
    }
    __syncthreads();
  }

  // ---- epilogue: scatter-accumulate valid rows into out
  #pragma unroll
  for (int i = 0; i < 4; ++i) {
    #pragma unroll
    for (int r = 0; r < 4; ++r) {
      const int slot = t0 + wm + i * 16 + ((lane >> 4) << 2) + r;
      if (slot < cnt) {
        const int token = g_tok[e][slot];
        #pragma unroll
        for (int j = 0; j < 4; ++j) {
          const int col = n0 + wn2 + j * 16 + (lane & 15);
          atomicAdd(out + (size_t)token * HID + col, acc[i][j][r]);
        }
      }
    }
  }
}

extern "C" void kernel_launch(void* const* d_in, const int* in_sizes, int n_in,
                              void* d_out, int out_size, void* d_ws, size_t ws_size,
                              hipStream_t stream) {
  const float* x   = (const float*)d_in[0];
  const int*   idx = (const int*)d_in[1];
  const float* wgu = (const float*)d_in[2];
  const float* wd  = (const float*)d_in[3];
  float* out = (float*)d_out;
  unsigned short* act = (unsigned short*)d_ws;   // 64 MB

  hipMemsetAsync(d_out, 0, (size_t)out_size * sizeof(float), stream);

  k0_compact<<<1, 512, 0, stream>>>(idx);

  dim3 g1(INT_ / 128, T_TOK / 256, NE);        // (32, 4, 8)
  k1_gateup<<<g1, dim3(512), 0, stream>>>(x, wgu, act);

  dim3 g2(HID / 128, (T_TOK / 256) * 4, NE);   // (8, 16, 8) — y = mt*4|ks
  k2_down<<<g2, dim3(512), 0, stream>>>(act, wd, out);
}

// Round 8
// 361.609 us; speedup vs baseline: 1.2643x; 1.0336x over previous
//
#include <hip/hip_runtime.h>
#include <hip/hip_bf16.h>
#include <stdint.h>

#define T_TOK 1024
#define HID   1024
#define INT_  4096
#define NE    8

typedef __attribute__((ext_vector_type(4))) float f32x4;
typedef __attribute__((ext_vector_type(8))) short short8;

__device__ int g_tok[NE][T_TOK];   // compacted token list per expert
__device__ int g_cnt[NE];

__device__ __forceinline__ uint32_t pack2bf(float a, float b) {
  unsigned short ua = __builtin_bit_cast(unsigned short, (__bf16)a);
  unsigned short ub = __builtin_bit_cast(unsigned short, (__bf16)b);
  return (uint32_t)ua | ((uint32_t)ub << 16);
}

// ---------------- Kernel 0: per-expert token compaction ---------------------
__global__ void k0_compact(const int* __restrict__ mask)  // [T_TOK][NE]
{
  const int w    = threadIdx.x >> 6;
  const int lane = threadIdx.x & 63;
  if (w >= NE) return;
  const unsigned long long ltmask = (1ull << lane) - 1ull;
  int base = 0;
  #pragma unroll
  for (int c = 0; c < T_TOK / 64; ++c) {
    const int t = c * 64 + lane;
    const bool pred = mask[t * NE + w] != 0;
    const unsigned long long bal = __ballot(pred);
    if (pred) g_tok[w][base + __popcll(bal & ltmask)] = t;
    base += __popcll(bal);
  }
  if (lane == 0) g_cnt[w] = base;
}

// ---------------- Kernel 1: act[e,slot,i] = up * silu(gate) -----------------
// grid (INT_/128, T_TOK/256, NE), 512 threads (8 waves, 2m x 4n).
// B loads are n-major (DRAM-row friendly: per wave-instr two 512B runs),
// transpose-written to [n][k] bf16 LDS with ((r>>2)&7) XOR swizzle.
__global__ __launch_bounds__(512, 1)
void k1_gateup(const float* __restrict__ x,        // [T_TOK][HID]
               const float* __restrict__ wgu,      // [NE][HID][2*INT_]
               unsigned short* __restrict__ act)   // [NE][T_TOK][INT_] bf16 bits
{
  const int e   = blockIdx.z;
  const int cnt = g_cnt[e];
  const int mt  = blockIdx.y;
  const int t0  = mt * 256;
  if (t0 >= cnt) return;

  __shared__ char sA [256 * 64 * 2];   // [m][k] bf16, swizzled (32 KB)
  __shared__ char sBg[128 * 64 * 2];   // [n][k] bf16, swizzled (16 KB)
  __shared__ char sBu[128 * 64 * 2];   // (16 KB)

  const int nt   = blockIdx.x;         // 0..31
  const int tid  = threadIdx.x;
  const int lane = tid & 63;
  const int wv   = tid >> 6;           // 0..7
  const int wm   = (wv >> 2) * 128;    // wave m offset: 0 / 128
  const int wn   = (wv & 3) * 32;      // wave n offset: 0/32/64/96

  const float* wb = wgu + (size_t)e * HID * (2 * INT_);
  const int n0 = nt * 128;

  f32x4 accg[8][2], accu[8][2];
  #pragma unroll
  for (int i = 0; i < 8; ++i)
    #pragma unroll
    for (int j = 0; j < 2; ++j) {
      accg[i][j] = (f32x4){0.f, 0.f, 0.f, 0.f};
      accu[i][j] = (f32x4){0.f, 0.f, 0.f, 0.f};
    }

  const int a_m = tid >> 4;            // 0..31
  const int a_k = (tid & 15) * 4;      // f32 elems 0..60
  const int n4  = (tid & 31) * 4;      // B: n-quad 0..124
  const int k4  = (tid >> 5) * 4;      // B: k-quad 0..60

  int tokr[8];
  #pragma unroll
  for (int p = 0; p < 8; ++p) tokr[p] = g_tok[e][t0 + p * 32 + a_m];

  for (int kt = 0; kt < HID; kt += 64) {
    // ---- stage A: gathered x rows [256][64] f32 -> bf16 LDS [m][k]
    #pragma unroll
    for (int p = 0; p < 8; ++p) {
      const int m = p * 32 + a_m;
      f32x4 v = *(const f32x4*)(x + (size_t)tokr[p] * HID + kt + a_k);
      uint2 w; w.x = pack2bf(v[0], v[1]); w.y = pack2bf(v[2], v[3]);
      *(uint2*)(sA + m * 128 + ((a_k * 2) ^ ((m & 7) << 4))) = w;
    }
    // ---- stage Bg/Bu: n-major 4k x 4n quads, transpose-write to [n][k]
    {
      const float* sg = wb + (size_t)(kt + k4) * (2 * INT_) + n0 + n4;
      f32x4 ga = *(const f32x4*)(sg);
      f32x4 gb = *(const f32x4*)(sg + (2 * INT_));
      f32x4 gc = *(const f32x4*)(sg + 2 * (2 * INT_));
      f32x4 gd = *(const f32x4*)(sg + 3 * (2 * INT_));
      f32x4 ua = *(const f32x4*)(sg + INT_);
      f32x4 ub = *(const f32x4*)(sg + INT_ + (2 * INT_));
      f32x4 uc = *(const f32x4*)(sg + INT_ + 2 * (2 * INT_));
      f32x4 ud = *(const f32x4*)(sg + INT_ + 3 * (2 * INT_));
      #pragma unroll
      for (int j = 0; j < 4; ++j) {
        const int r = n4 + j;
        const int off = r * 128 + ((k4 * 2) ^ (((r >> 2) & 7) << 4));
        uint2 wg; wg.x = pack2bf(ga[j], gb[j]); wg.y = pack2bf(gc[j], gd[j]);
        *(uint2*)(sBg + off) = wg;
        uint2 wu; wu.x = pack2bf(ua[j], ub[j]); wu.y = pack2bf(uc[j], ud[j]);
        *(uint2*)(sBu + off) = wu;
      }
    }
    __syncthreads();
    // ---- compute tile kt from LDS
    #pragma unroll
    for (int ks = 0; ks < 2; ++ks) {
      const int kfb = ks * 64 + ((lane >> 4) << 4);
      short8 af[8], bg[2], bu[2];
      #pragma unroll
      for (int i = 0; i < 8; ++i) {
        const int r = wm + i * 16 + (lane & 15);
        af[i] = *(const short8*)(sA + r * 128 + (kfb ^ ((r & 7) << 4)));
      }
      #pragma unroll
      for (int j = 0; j < 2; ++j) {
        const int r = wn + j * 16 + (lane & 15);
        const int off = r * 128 + (kfb ^ (((r >> 2) & 7) << 4));
        bg[j] = *(const short8*)(sBg + off);
        bu[j] = *(const short8*)(sBu + off);
      }
      #pragma unroll
      for (int i = 0; i < 8; ++i)
        #pragma unroll
        for (int j = 0; j < 2; ++j) {
          accg[i][j] = __builtin_amdgcn_mfma_f32_16x16x32_bf16(af[i], bg[j], accg[i][j], 0, 0, 0);
          accu[i][j] = __builtin_amdgcn_mfma_f32_16x16x32_bf16(af[i], bu[j], accu[i][j], 0, 0, 0);
        }
    }
    __syncthreads();
  }

  // ---- epilogue: act = up * silu(gate)
  unsigned short* ab = act + (size_t)e * T_TOK * INT_;
  #pragma unroll
  for (int i = 0; i < 8; ++i) {
    #pragma unroll
    for (int r = 0; r < 4; ++r) {
      const int slot = t0 + wm + i * 16 + ((lane >> 4) << 2) + r;
      if (slot < cnt) {
        #pragma unroll
        for (int j = 0; j < 2; ++j) {
          const int col = n0 + wn + j * 16 + (lane & 15);
          const float g = accg[i][j][r];
          const float u = accu[i][j][r];
          const float s = u * g / (1.f + __expf(-g));
          ab[(size_t)slot * INT_ + col] = __builtin_bit_cast(unsigned short, (__bf16)s);
        }
      }
    }
  }
}

// ---------------- Kernel 2: out[tok[slot],h] += act[e,slot] @ w_down[e] -----
// grid (HID/128, (T_TOK/256)*4, NE), 512 threads (8 waves, 4m x 2n).
// K split 4-way. B loads n-major + transpose-write (same scheme as k1).
__global__ __launch_bounds__(512, 1)
void k2_down(const unsigned short* __restrict__ act,  // [NE][T_TOK][INT_] bf16
             const float* __restrict__ wd,            // [NE][INT_][HID]
             float* __restrict__ out)                 // [T_TOK][HID]
{
  const int e   = blockIdx.z;
  const int cnt = g_cnt[e];
  const int mt  = blockIdx.y >> 2;     // 0..3
  const int ks4 = blockIdx.y & 3;      // K-slice 0..3
  const int t0  = mt * 256;
  if (t0 >= cnt) return;

  __shared__ char sA[256 * 64 * 2];    // [m][k] bf16 (32 KB)
  __shared__ char sB[128 * 64 * 2];    // [n][k] bf16 (16 KB)

  const int nt   = blockIdx.x;         // 0..7
  const int tid  = threadIdx.x;
  const int lane = tid & 63;
  const int wv   = tid >> 6;           // 0..7
  const int wm   = (wv >> 1) * 64;     // 0/64/128/192
  const int wn2  = (wv & 1) * 64;      // 0/64

  const unsigned short* ab = act + (size_t)e * T_TOK * INT_;
  const float* wb = wd + (size_t)e * INT_ * HID;
  const int n0 = nt * 128;

  f32x4 acc[4][4];
  #pragma unroll
  for (int i = 0; i < 4; ++i)
    #pragma unroll
    for (int j = 0; j < 4; ++j) acc[i][j] = (f32x4){0.f, 0.f, 0.f, 0.f};

  const int a_m = tid >> 3;            // 0..63
  const int a_k = (tid & 7) * 8;       // bf16 elems 0..56
  const int n4  = (tid & 31) * 4;      // B: n-quad 0..124
  const int k4  = (tid >> 5) * 4;      // B: k-quad 0..60

  const int kbeg = ks4 * (INT_ / 4);
  const int kend = kbeg + (INT_ / 4);

  for (int kt = kbeg; kt < kend; kt += 64) {
    // ---- stage A: act tile [256][64] (already bf16), direct 16B copies
    #pragma unroll
    for (int p = 0; p < 4; ++p) {
      const int m = p * 64 + a_m;
      uint4 v = *(const uint4*)(ab + (size_t)(t0 + m) * INT_ + kt + a_k);
      *(uint4*)(sA + m * 128 + ((a_k * 2) ^ ((m & 7) << 4))) = v;
    }
    // ---- stage B: n-major 4k x 4n quads, transpose-write to [n][k]
    {
      const float* src = wb + (size_t)(kt + k4) * HID + n0 + n4;
      f32x4 r0 = *(const f32x4*)(src);
      f32x4 r1 = *(const f32x4*)(src + HID);
      f32x4 r2 = *(const f32x4*)(src + 2 * HID);
      f32x4 r3 = *(const f32x4*)(src + 3 * HID);
      #pragma unroll
      for (int j = 0; j < 4; ++j) {
        const int r = n4 + j;
        const int off = r * 128 + ((k4 * 2) ^ (((r >> 2) & 7) << 4));
        uint2 w; w.x = pack2bf(r0[j], r1[j]); w.y = pack2bf(r2[j], r3[j]);
        *(uint2*)(sB + off) = w;
      }
    }
    __syncthreads();
    #pragma unroll
    for (int ks = 0; ks < 2; ++ks) {
      const int kfb = ks * 64 + ((lane >> 4) << 4);
      short8 af[4], bf[4];
      #pragma unroll
      for (int i = 0; i < 4; ++i) {
        const int r = wm + i * 16 + (lane & 15);
        af[i] = *(const short8*)(sA + r * 128 + (kfb ^ ((r & 7) << 4)));
      }
      #pragma unroll
      for (int j = 0; j < 4; ++j) {
        const int r = wn2 + j * 16 + (lane & 15);
        bf[j] = *(const short8*)(sB + r * 128 + (kfb ^ (((r >> 2) & 7) << 4)));
      }
      #pragma unroll
      for (int i = 0; i < 4; ++i)
        #pragma unroll
        for (int j = 0; j < 4; ++j)
          acc[i][j] = __builtin_amdgcn_mfma_f32_16x16x32_bf16(af[i], bf[j], acc[i][j], 0, 0, 0);
    }
    __syncthreads();
  }

  // ---- epilogue: scatter-accumulate valid rows into out
  #pragma unroll
  for (int i = 0; i < 4; ++i) {
    #pragma unroll
    for (int r = 0; r < 4; ++r) {
      const int slot = t0 + wm + i * 16 + ((lane >> 4) << 2) + r;
      if (slot < cnt) {
        const int token = g_tok[e][slot];
        #pragma unroll
        for (int j = 0; j < 4; ++j) {
          const int col = n0 + wn2 + j * 16 + (lane & 15);
          atomicAdd(out + (size_t)token * HID + col, acc[i][j][r]);
        }
      }
    }
  }
}

extern "C" void kernel_launch(void* const* d_in, const int* in_sizes, int n_in,
                              void* d_out, int out_size, void* d_ws, size_t ws_size,
                              hipStream_t stream) {
  const float* x   = (const float*)d_in[0];
  const int*   idx = (const int*)d_in[1];
  const float* wgu = (const float*)d_in[2];
  const float* wd  = (const float*)d_in[3];
  float* out = (float*)d_out;
  unsigned short* act = (unsigned short*)d_ws;   // 64 MB

  hipMemsetAsync(d_out, 0, (size_t)out_size * sizeof(float), stream);

  k0_compact<<<1, 512, 0, stream>>>(idx);

  dim3 g1(INT_ / 128, T_TOK / 256, NE);        // (32, 4, 8)
  k1_gateup<<<g1, dim3(512), 0, stream>>>(x, wgu, act);

  dim3 g2(HID / 128, (T_TOK / 256) * 4, NE);   // (8, 16, 8) — y = mt*4|ks
  k2_down<<<g2, dim3(512), 0, stream>>>(act, wd, out);
}